// Round 7
// baseline (1268.595 us; speedup 1.0000x reference)
//
#include <hip/hip_runtime.h>

#define N_NODES 100000
#define N_EDGES 1200000
#define DIM     64
#define N_LAYERS 3
#define N_GRAPHS 512
#define OUTD    192   // 3 * 64, concat layout
#define BN_EPS  1e-5f

#define ELL_CAP 48        // max in-degree capacity (Poisson(12) tail @48 ~3e-15)

#define BSHIFT 9
#define BWIDTH (1 << BSHIFT)                              // 512 nodes / bucket
#define NBUCK ((N_NODES + BWIDTH - 1) >> BSHIFT)          // 196
#define BCAP 8192         // bucket capacity (~6.1k expected, +26 sigma)

#define SCAN_CHUNK 1024
#define NBLK ((N_NODES + SCAN_CHUNK - 1) / SCAN_CHUNK)    // 98

#define NPB 64            // nodes per block in layer_kernel
#define LDS_PITCH 65      // +1 pad -> 2-way bank aliasing only (free)
#define NLBLK ((N_NODES + NPB - 1) / NPB)                 // 1563

// ---------------------------------------------------------------------------
// Transpose W1/W2 (per layer): WT[l][k][j] = W[l][j][k]. Also writes the
// identity affine block (scale=1, shift=0) used by layer 0.
__global__ void transpose_w(const float* __restrict__ W1, const float* __restrict__ W2,
                            float* __restrict__ W1T, float* __restrict__ W2T,
                            float* __restrict__ idaff) {
    int idx = blockIdx.x * blockDim.x + threadIdx.x;  // L*64*64
    if (idx < 128) idaff[idx] = (idx < 64) ? 1.0f : 0.0f;
    if (idx >= N_LAYERS * DIM * DIM) return;
    int l = idx >> 12;
    int r = idx & 4095;
    int j = r >> 6;
    int k = r & 63;
    int dstp = (l << 12) + k * DIM + j;
    W1T[dstp] = W1[idx];
    W2T[dstp] = W2[idx];
}

// ---------------------------------------------------------------------------
// Two-phase ELL binning.
// Phase 1: scatter edges into coarse buckets by dst>>9. Atomic-cursor returns
// are dense -> consecutive 8B writes pack into the same cache lines
// (write-combining), avoiding per-edge line amplification.
// Entry packs src (17b) | dst-low-9 (<<20) in .x, weight bits in .y.
__global__ void bucket_scatter(const int* __restrict__ src, const int* __restrict__ dst,
                               const float* __restrict__ ew,
                               int* __restrict__ bcur, int2* __restrict__ buck) {
    int e = blockIdx.x * blockDim.x + threadIdx.x;
    if (e >= N_EDGES) return;
    int t = dst[e];
    int b = t >> BSHIFT;
    int pos = atomicAdd(&bcur[b], 1);
    if (pos < BCAP)
        buck[(size_t)b * BCAP + pos] =
            make_int2(src[e] | ((t & (BWIDTH - 1)) << 20), __float_as_int(ew[e]));
}

// Phase 2: one block per bucket; spread the bucket's edges into its 512-node
// ELL window (512*48*8 = 192 KB, L2-resident -> scatter amplification stays
// on-chip; final write-back is dirty data only).
__global__ void bucket_to_ell(const int2* __restrict__ buck,
                              const int* __restrict__ bcur,
                              int* __restrict__ cnt, int2* __restrict__ pe) {
    int b = blockIdx.x;
    int nE = bcur[b];
    if (nE > BCAP) nE = BCAP;
    for (int i = threadIdx.x; i < nE; i += blockDim.x) {
        int2 p = buck[(size_t)b * BCAP + i];
        int sv = p.x & 0xFFFFF;
        int node = (b << BSHIFT) + ((p.x >> 20) & (BWIDTH - 1));
        int pos = atomicAdd(&cnt[node], 1);
        if (pos < ELL_CAP)
            pe[(size_t)node * ELL_CAP + pos] = make_int2(sv, p.y);
    }
}

// ---------------------------------------------------------------------------
// CSR fallback path (only if ws too small for ELL).
__global__ void hist_kernel(const int* __restrict__ dst, int* __restrict__ counts) {
    int e = blockIdx.x * blockDim.x + threadIdx.x;
    if (e >= N_EDGES) return;
    atomicAdd(&counts[dst[e]], 1);
}

__global__ void scan_partial(const int* __restrict__ C, int* __restrict__ bsum) {
    __shared__ int lds[256];
    int b = blockIdx.x, t = threadIdx.x;
    int base = b * SCAN_CHUNK + t * 4;
    int s = 0;
#pragma unroll
    for (int k = 0; k < 4; ++k) {
        int i = base + k;
        if (i < N_NODES) s += C[i];
    }
    lds[t] = s;
    __syncthreads();
    for (int o = 128; o > 0; o >>= 1) {
        if (t < o) lds[t] += lds[t + o];
        __syncthreads();
    }
    if (t == 0) bsum[b] = lds[0];
}

__global__ void scan_bsum(int* __restrict__ bsum) {
    __shared__ int lds[128];
    int t = threadIdx.x;
    int v = (t < NBLK) ? bsum[t] : 0;
    lds[t] = v;
    __syncthreads();
    for (int o = 1; o < 128; o <<= 1) {
        int add = (t >= o) ? lds[t - o] : 0;
        __syncthreads();
        lds[t] += add;
        __syncthreads();
    }
    if (t < NBLK) bsum[t] = lds[t] - v;   // exclusive
}

__global__ void scan_final(const int* __restrict__ C, const int* __restrict__ bsum,
                           int* __restrict__ O, int* __restrict__ cursor) {
    __shared__ int lds[256];
    int b = blockIdx.x, t = threadIdx.x;
    int base = b * SCAN_CHUNK + t * 4;
    int v[4];
    int s = 0;
#pragma unroll
    for (int k = 0; k < 4; ++k) {
        int i = base + k;
        v[k] = (i < N_NODES) ? C[i] : 0;
        s += v[k];
    }
    lds[t] = s;
    __syncthreads();
    for (int o = 1; o < 256; o <<= 1) {
        int add = (t >= o) ? lds[t - o] : 0;
        __syncthreads();
        lds[t] += add;
        __syncthreads();
    }
    int off = bsum[b] + (lds[t] - s);
#pragma unroll
    for (int k = 0; k < 4; ++k) {
        int i = base + k;
        if (i < N_NODES) {
            O[i] = off;
            cursor[i] = off;
            off += v[k];
            if (i == N_NODES - 1) O[N_NODES] = off;
        }
    }
}

__global__ void edge_bin_csr(const int* __restrict__ src, const int* __restrict__ dst,
                             const float* __restrict__ ew,
                             int* __restrict__ cursor, int2* __restrict__ pe) {
    int e = blockIdx.x * blockDim.x + threadIdx.x;
    if (e >= N_EDGES) return;
    int t = dst[e];
    int pos = atomicAdd(&cursor[t], 1);
    pe[pos] = make_int2(src[e], __float_as_int(ew[e]));
}

// ---------------------------------------------------------------------------
// Fused layer (compile-time specialized on edge layout): gather(+x,
// +input-BN-affine, wsum inline) -> LDS -> MLP1 -> relu -> MLP2 -> relu
// -> global write + per-block BN stat partials.
// Block = 256 threads = 4 waves, 64 nodes; node id wave-uniform in gather so
// edge (src,w) pairs are s_loads; x_in[src] row is one coalesced 256B load.
// Input BN affine folded: agg_bn = sc*(x[n]+Σw·x[s]) + sh*(1+Σw).
template <bool ELL>
__global__ void __launch_bounds__(256) layer_kernel(
    const float* __restrict__ x_in, int xstride,
    const int* __restrict__ seg,     // ELL: counts; CSR: offsets (N+1)
    const int2* __restrict__ pe,
    const float* __restrict__ affine /* [128]: scale|shift of input */,
    const float* __restrict__ W1T, const float* __restrict__ b1,
    const float* __restrict__ W2T, const float* __restrict__ b2,
    float* __restrict__ out /* xs base + layer*64, row stride OUTD */,
    float* __restrict__ pstat /* [NLBLK][128]: sum|sumsq partials */) {
    __shared__ float lds[NPB * LDS_PITCH];
    int t = threadIdx.x;
    int lane = t & 63;
    int wid = __builtin_amdgcn_readfirstlane(t >> 6);   // wave id 0..3, SGPR
    int nbase = blockIdx.x * NPB;

    float sc_in = affine[lane];          // coalesced 256B, once
    float sh_in = affine[64 + lane];

    // ---- Phase 1: gather (16 nodes per wave, node id wave-uniform) ----
    for (int nn = 0; nn < 16; ++nn) {
        int n = nbase + wid * 16 + nn;
        float acc = 0.0f;
        if (n < N_NODES) {
            int beg, end;
            if (ELL) { beg = n * ELL_CAP; end = beg + seg[n]; }
            else     { beg = seg[n];      end = seg[n + 1]; }
            acc = x_in[(size_t)n * xstride + lane];   // coalesced 256B
            float a1 = 0.0f;
            float ws = 0.0f;                          // Σ edge weights
            int e = beg;
            for (; e + 2 <= end; e += 2) {
                int2 p0 = pe[e];
                int2 p1 = pe[e + 1];
                float w0 = __int_as_float(p0.y);
                float w1 = __int_as_float(p1.y);
                acc = fmaf(w0, x_in[(size_t)p0.x * xstride + lane], acc);
                a1  = fmaf(w1, x_in[(size_t)p1.x * xstride + lane], a1);
                ws += w0 + w1;
            }
            if (e < end) {
                int2 p = pe[e];
                float w = __int_as_float(p.y);
                a1 = fmaf(w, x_in[(size_t)p.x * xstride + lane], a1);
                ws += w;
            }
            acc = fmaf(sc_in, acc + a1, sh_in * (1.0f + ws));
        }
        lds[(wid * 16 + nn) * LDS_PITCH + lane] = acc;
    }
    __syncthreads();

    // ---- Stage 1 GEMM: hidden = relu(xin @ W1^T + b1) ----
    float h[16];
#pragma unroll
    for (int jj = 0; jj < 16; ++jj) h[jj] = b1[wid * 16 + jj];
#pragma unroll 4
    for (int k = 0; k < DIM; ++k) {
        float xv = lds[lane * LDS_PITCH + k];
        const float* wr = W1T + k * DIM + wid * 16;   // uniform -> s_load
#pragma unroll
        for (int jj = 0; jj < 16; ++jj) h[jj] = fmaf(xv, wr[jj], h[jj]);
    }
#pragma unroll
    for (int jj = 0; jj < 16; ++jj) h[jj] = fmaxf(h[jj], 0.0f);
    __syncthreads();          // all lds (xin) reads done
#pragma unroll
    for (int jj = 0; jj < 16; ++jj) lds[lane * LDS_PITCH + wid * 16 + jj] = h[jj];
    __syncthreads();

    // ---- Stage 2 GEMM: o = relu(hidden @ W2^T + b2) ----
    float o[16];
#pragma unroll
    for (int jj = 0; jj < 16; ++jj) o[jj] = b2[wid * 16 + jj];
#pragma unroll 4
    for (int k = 0; k < DIM; ++k) {
        float hv = lds[lane * LDS_PITCH + k];
        const float* wr = W2T + k * DIM + wid * 16;
#pragma unroll
        for (int jj = 0; jj < 16; ++jj) o[jj] = fmaf(hv, wr[jj], o[jj]);
    }
    int n = nbase + lane;
    bool valid = (n < N_NODES);
#pragma unroll
    for (int jj = 0; jj < 16; ++jj) o[jj] = fmaxf(o[jj], 0.0f);
    if (valid) {
        float* orow = out + (size_t)n * OUTD + wid * 16;
#pragma unroll
        for (int jj = 0; jj < 16; jj += 4) {
            *(float4*)(orow + jj) = make_float4(o[jj], o[jj + 1], o[jj + 2], o[jj + 3]);
        }
    }

    // ---- BN stat partials: butterfly over 64 lanes; wave wid owns dims
    // [wid*16, wid*16+16). Non-atomic coalesced per-block store.
    float my_s = 0.0f, my_q = 0.0f;
#pragma unroll
    for (int jj = 0; jj < 16; ++jj) {
        float v = valid ? o[jj] : 0.0f;
        float vs = v, vq = v * v;
#pragma unroll
        for (int m = 1; m < 64; m <<= 1) {
            vs += __shfl_xor(vs, m);
            vq += __shfl_xor(vq, m);
        }
        if (lane == jj) { my_s = vs; my_q = vq; }
    }
    if (lane < 16) {
        size_t base = (size_t)blockIdx.x * 128 + wid * 16 + lane;
        pstat[base] = my_s;
        pstat[base + 64] = my_q;
    }
}

// ---------------------------------------------------------------------------
// Reduce per-block BN partials -> scale/shift for one layer (bn_prep folded).
__global__ void __launch_bounds__(1024) reduce_stats(
    const float* __restrict__ pstat,
    const float* __restrict__ gamma, const float* __restrict__ beta,
    float* __restrict__ ss /* [128]: scale|shift */) {
    __shared__ double part[8][128];
    __shared__ double tot[128];
    int t = threadIdx.x;
    int d = t & 127;
    int g = t >> 7;
    double s = 0.0;
    for (int b = g; b < NLBLK; b += 8)
        s += (double)pstat[(size_t)b * 128 + d];
    part[g][d] = s;
    __syncthreads();
    if (t < 128) {
        double x = 0.0;
#pragma unroll
        for (int k = 0; k < 8; ++k) x += part[k][d];
        tot[d] = x;
    }
    __syncthreads();
    if (t < 64) {
        double mu = tot[t] / (double)N_NODES;
        double var = tot[64 + t] / (double)N_NODES - mu * mu;
        float inv = (float)(1.0 / sqrt(var + (double)BN_EPS));
        float sc = gamma[t] * inv;
        ss[t] = sc;
        ss[64 + t] = beta[t] - (float)mu * sc;
    }
}

// ---------------------------------------------------------------------------
// Final pass: apply BN affine to xs IN PLACE (all 3 layers at once) and
// add-pool per graph. Grid (512 graphs, 4 parts), block 192.
__global__ void bn_pool(float* __restrict__ xs,
                        const int* __restrict__ batch,
                        const float* __restrict__ ss /* [3][128] */,
                        float* __restrict__ pooled) {
    int g = blockIdx.x;
    int part = blockIdx.y;   // 0..3
    int d = threadIdx.x;     // 0..191
    int l = d >> 6, dd = d & 63;
    float sc = ss[l * 128 + dd];
    float sh = ss[l * 128 + 64 + dd];
    int start, end;
    {
        int lo = 0, hi = N_NODES;
        while (lo < hi) { int m = (lo + hi) >> 1; if (batch[m] < g) lo = m + 1; else hi = m; }
        start = lo;
    }
    {
        int lo = start, hi = N_NODES;
        while (lo < hi) { int m = (lo + hi) >> 1; if (batch[m] <= g) lo = m + 1; else hi = m; }
        end = lo;
    }
    float acc = 0.0f;
    for (int n = start + part; n < end; n += 4) {
        float* p = xs + (size_t)n * OUTD + d;
        float v = fmaf(*p, sc, sh);
        *p = v;
        acc += v;
    }
    atomicAdd(&pooled[(size_t)g * OUTD + d], acc);
}

// ---------------------------------------------------------------------------
extern "C" void kernel_launch(void* const* d_in, const int* in_sizes, int n_in,
                              void* d_out, int out_size, void* d_ws, size_t ws_size,
                              hipStream_t stream) {
    const float* x0    = (const float*)d_in[0];
    const int*   ei    = (const int*)d_in[1];
    const float* ew    = (const float*)d_in[2];
    const int*   batch = (const int*)d_in[3];
    const float* W1    = (const float*)d_in[5];
    const float* b1    = (const float*)d_in[6];
    const float* W2    = (const float*)d_in[7];
    const float* b2    = (const float*)d_in[8];
    const float* gamma = (const float*)d_in[9];
    const float* beta  = (const float*)d_in[10];

    float* pooled = (float*)d_out;                      // [512, 192]
    float* xs     = pooled + (size_t)N_GRAPHS * OUTD;   // [100000, 192]

    const int* src = ei;
    const int* dst = ei + N_EDGES;

    const size_t aux_floats = (size_t)2 * N_LAYERS * DIM * DIM + 128
                            + (size_t)N_LAYERS * 128 + (size_t)NLBLK * 128;

    // ELL layout: pe[N*CAP] | buck[NBUCK*BCAP] | cnt[N+4] | bcur[NBUCK+4] | aux
    const size_t ell_bytes = (size_t)N_NODES * ELL_CAP * sizeof(int2)
                           + (size_t)NBUCK * BCAP * sizeof(int2)
                           + (size_t)(N_NODES + 4) * sizeof(int)
                           + (size_t)(NBUCK + 4) * sizeof(int)
                           + aux_floats * sizeof(float);
    bool use_ell = (ws_size >= ell_bytes);

    int2*  pe;
    int*   seg;        // ELL: counts; CSR: offsets
    float* W1T;
    int2*  buck = nullptr;
    int*   bcur = nullptr;
    int*   csr_counts = nullptr;
    int*   csr_cursor = nullptr;
    int*   csr_bsum   = nullptr;

    if (use_ell) {
        pe   = (int2*)d_ws;                                   // 38.4 MB
        buck = pe + (size_t)N_NODES * ELL_CAP;                // 12.8 MB
        seg  = (int*)(buck + (size_t)NBUCK * BCAP);           // cnt (N+4)
        bcur = seg + N_NODES + 4;                             // (NBUCK+4)
        W1T  = (float*)(bcur + NBUCK + 4);
    } else {
        pe   = (int2*)d_ws;                                   // 9.6 MB
        csr_counts = (int*)(pe + N_EDGES);                    // (N+4)
        seg        = csr_counts + N_NODES + 4;                // offsets (N+4)
        csr_cursor = seg + N_NODES + 4;                       // (N+4)
        csr_bsum   = csr_cursor + N_NODES + 4;                // 128
        W1T  = (float*)(csr_bsum + 128);
    }
    float* W2T   = W1T + N_LAYERS * DIM * DIM;
    float* idaff = W2T + N_LAYERS * DIM * DIM;     // 128 floats
    float* ss    = idaff + 128;                    // 3*128 floats
    float* pstat = ss + N_LAYERS * 128;            // NLBLK*128 floats

    transpose_w<<<(N_LAYERS * DIM * DIM + 255) / 256, 256, 0, stream>>>(
        W1, W2, W1T, W2T, idaff);

    if (use_ell) {
        // cnt and bcur are contiguous -> one memset.
        hipMemsetAsync(seg, 0, (size_t)(N_NODES + 4 + NBUCK + 4) * sizeof(int), stream);
        bucket_scatter<<<(N_EDGES + 255) / 256, 256, 0, stream>>>(src, dst, ew, bcur, buck);
        bucket_to_ell<<<NBUCK, 256, 0, stream>>>(buck, bcur, seg, pe);
    } else {
        hipMemsetAsync(csr_counts, 0, (size_t)(N_NODES + 4) * sizeof(int), stream);
        hist_kernel<<<(N_EDGES + 255) / 256, 256, 0, stream>>>(dst, csr_counts);
        scan_partial<<<NBLK, 256, 0, stream>>>(csr_counts, csr_bsum);
        scan_bsum<<<1, 128, 0, stream>>>(csr_bsum);
        scan_final<<<NBLK, 256, 0, stream>>>(csr_counts, csr_bsum, seg, csr_cursor);
        edge_bin_csr<<<(N_EDGES + 255) / 256, 256, 0, stream>>>(src, dst, ew,
                                                                csr_cursor, pe);
    }

    for (int i = 0; i < N_LAYERS; ++i) {
        const float* xin = (i == 0) ? x0 : (xs + (size_t)(i - 1) * DIM);
        int xstride = (i == 0) ? DIM : OUTD;
        const float* affine = (i == 0) ? idaff : (ss + (size_t)(i - 1) * 128);

        if (use_ell) {
            layer_kernel<true><<<NLBLK, 256, 0, stream>>>(
                xin, xstride, seg, pe, affine,
                W1T + (size_t)i * DIM * DIM, b1 + (size_t)i * DIM,
                W2T + (size_t)i * DIM * DIM, b2 + (size_t)i * DIM,
                xs + (size_t)i * DIM, pstat);
        } else {
            layer_kernel<false><<<NLBLK, 256, 0, stream>>>(
                xin, xstride, seg, pe, affine,
                W1T + (size_t)i * DIM * DIM, b1 + (size_t)i * DIM,
                W2T + (size_t)i * DIM * DIM, b2 + (size_t)i * DIM,
                xs + (size_t)i * DIM, pstat);
        }

        reduce_stats<<<1, 1024, 0, stream>>>(
            pstat, gamma + (size_t)i * DIM, beta + (size_t)i * DIM,
            ss + (size_t)i * 128);
    }

    hipMemsetAsync(pooled, 0, (size_t)N_GRAPHS * OUTD * sizeof(float), stream);
    dim3 pgrid(N_GRAPHS, 4);
    bn_pool<<<pgrid, OUTD, 0, stream>>>(xs, batch, ss, pooled);
}

// Round 8
// 648.569 us; speedup vs baseline: 1.9560x; 1.9560x over previous
//
#include <hip/hip_runtime.h>

#define N_NODES 100000
#define N_EDGES 1200000
#define DIM     64
#define N_LAYERS 3
#define N_GRAPHS 512
#define OUTD    192   // 3 * 64, concat layout
#define BN_EPS  1e-5f

#define ELL_CAP 48        // max in-degree capacity (Poisson(12) tail @48 ~1e-15)

#define SCAN_CHUNK 1024
#define NBLK ((N_NODES + SCAN_CHUNK - 1) / SCAN_CHUNK)    // 98

#define NPB 64            // nodes per block in layer_kernel
#define LDS_PITCH 65      // +1 pad -> 2-way bank aliasing only (free)
#define NLBLK ((N_NODES + NPB - 1) / NPB)                 // 1563

// ---------------------------------------------------------------------------
// Transpose W1/W2 (per layer): WT[l][k][j] = W[l][j][k]. Also writes the
// identity affine block (scale=1, shift=0) used by layer 0.
__global__ void transpose_w(const float* __restrict__ W1, const float* __restrict__ W2,
                            float* __restrict__ W1T, float* __restrict__ W2T,
                            float* __restrict__ idaff) {
    int idx = blockIdx.x * blockDim.x + threadIdx.x;  // L*64*64
    if (idx < 128) idaff[idx] = (idx < 64) ? 1.0f : 0.0f;
    if (idx >= N_LAYERS * DIM * DIM) return;
    int l = idx >> 12;
    int r = idx & 4095;
    int j = r >> 6;
    int k = r & 63;
    int dstp = (l << 12) + k * DIM + j;
    W1T[dstp] = W1[idx];
    W2T[dstp] = W2[idx];
}

// ---------------------------------------------------------------------------
// ELL binning, single pass (PROVEN R6): 1.2M atomics spread over 100k node
// cursors (~12/address -> negligible contention; cf. R7's 196-cursor disaster).
// cursor[] ends up holding the per-node count.
__global__ void edge_bin_ell(const int* __restrict__ src, const int* __restrict__ dst,
                             const float* __restrict__ ew,
                             int* __restrict__ cursor, int2* __restrict__ pe) {
    int e = blockIdx.x * blockDim.x + threadIdx.x;
    if (e >= N_EDGES) return;
    int t = dst[e];
    int pos = atomicAdd(&cursor[t], 1);
    if (pos < ELL_CAP)
        pe[(size_t)t * ELL_CAP + pos] = make_int2(src[e], __float_as_int(ew[e]));
}

// ---------------------------------------------------------------------------
// CSR fallback path (only if ws too small for ELL).
__global__ void hist_kernel(const int* __restrict__ dst, int* __restrict__ counts) {
    int e = blockIdx.x * blockDim.x + threadIdx.x;
    if (e >= N_EDGES) return;
    atomicAdd(&counts[dst[e]], 1);
}

__global__ void scan_partial(const int* __restrict__ C, int* __restrict__ bsum) {
    __shared__ int lds[256];
    int b = blockIdx.x, t = threadIdx.x;
    int base = b * SCAN_CHUNK + t * 4;
    int s = 0;
#pragma unroll
    for (int k = 0; k < 4; ++k) {
        int i = base + k;
        if (i < N_NODES) s += C[i];
    }
    lds[t] = s;
    __syncthreads();
    for (int o = 128; o > 0; o >>= 1) {
        if (t < o) lds[t] += lds[t + o];
        __syncthreads();
    }
    if (t == 0) bsum[b] = lds[0];
}

__global__ void scan_bsum(int* __restrict__ bsum) {
    __shared__ int lds[128];
    int t = threadIdx.x;
    int v = (t < NBLK) ? bsum[t] : 0;
    lds[t] = v;
    __syncthreads();
    for (int o = 1; o < 128; o <<= 1) {
        int add = (t >= o) ? lds[t - o] : 0;
        __syncthreads();
        lds[t] += add;
        __syncthreads();
    }
    if (t < NBLK) bsum[t] = lds[t] - v;   // exclusive
}

__global__ void scan_final(const int* __restrict__ C, const int* __restrict__ bsum,
                           int* __restrict__ O, int* __restrict__ cursor) {
    __shared__ int lds[256];
    int b = blockIdx.x, t = threadIdx.x;
    int base = b * SCAN_CHUNK + t * 4;
    int v[4];
    int s = 0;
#pragma unroll
    for (int k = 0; k < 4; ++k) {
        int i = base + k;
        v[k] = (i < N_NODES) ? C[i] : 0;
        s += v[k];
    }
    lds[t] = s;
    __syncthreads();
    for (int o = 1; o < 256; o <<= 1) {
        int add = (t >= o) ? lds[t - o] : 0;
        __syncthreads();
        lds[t] += add;
        __syncthreads();
    }
    int off = bsum[b] + (lds[t] - s);
#pragma unroll
    for (int k = 0; k < 4; ++k) {
        int i = base + k;
        if (i < N_NODES) {
            O[i] = off;
            cursor[i] = off;
            off += v[k];
            if (i == N_NODES - 1) O[N_NODES] = off;
        }
    }
}

__global__ void edge_bin_csr(const int* __restrict__ src, const int* __restrict__ dst,
                             const float* __restrict__ ew,
                             int* __restrict__ cursor, int2* __restrict__ pe) {
    int e = blockIdx.x * blockDim.x + threadIdx.x;
    if (e >= N_EDGES) return;
    int t = dst[e];
    int pos = atomicAdd(&cursor[t], 1);
    pe[pos] = make_int2(src[e], __float_as_int(ew[e]));
}

// ---------------------------------------------------------------------------
// Fused layer (compile-time specialized on edge layout): gather(+x,
// +input-BN-affine, wsum inline) -> LDS -> MLP1 -> relu -> MLP2 -> relu
// -> global write + per-block BN stat partials.
// Block = 256 threads = 4 waves, 64 nodes; node id wave-uniform in gather so
// edge (src,w) pairs are s_loads; x_in[src] row is one coalesced 256B load.
// Input BN affine folded: agg_bn = sc*(x[n]+Σw·x[s]) + sh*(1+Σw).
template <bool ELL>
__global__ void __launch_bounds__(256) layer_kernel(
    const float* __restrict__ x_in, int xstride,
    const int* __restrict__ seg,     // ELL: counts; CSR: offsets (N+1)
    const int2* __restrict__ pe,
    const float* __restrict__ affine /* [128]: scale|shift of input */,
    const float* __restrict__ W1T, const float* __restrict__ b1,
    const float* __restrict__ W2T, const float* __restrict__ b2,
    float* __restrict__ out /* xs base + layer*64, row stride OUTD */,
    float* __restrict__ pstat /* [NLBLK][128]: sum|sumsq partials */) {
    __shared__ float lds[NPB * LDS_PITCH];
    int t = threadIdx.x;
    int lane = t & 63;
    int wid = __builtin_amdgcn_readfirstlane(t >> 6);   // wave id 0..3, SGPR
    int nbase = blockIdx.x * NPB;

    float sc_in = affine[lane];          // coalesced 256B, once
    float sh_in = affine[64 + lane];

    // ---- Phase 1: gather (16 nodes per wave, node id wave-uniform) ----
    for (int nn = 0; nn < 16; ++nn) {
        int n = nbase + wid * 16 + nn;
        float acc = 0.0f;
        if (n < N_NODES) {
            int beg, end;
            if (ELL) { beg = n * ELL_CAP; end = beg + seg[n]; }
            else     { beg = seg[n];      end = seg[n + 1]; }
            acc = x_in[(size_t)n * xstride + lane];   // coalesced 256B
            float a1 = 0.0f;
            float ws = 0.0f;                          // Σ edge weights
            int e = beg;
            for (; e + 2 <= end; e += 2) {
                int2 p0 = pe[e];
                int2 p1 = pe[e + 1];
                float w0 = __int_as_float(p0.y);
                float w1 = __int_as_float(p1.y);
                acc = fmaf(w0, x_in[(size_t)p0.x * xstride + lane], acc);
                a1  = fmaf(w1, x_in[(size_t)p1.x * xstride + lane], a1);
                ws += w0 + w1;
            }
            if (e < end) {
                int2 p = pe[e];
                float w = __int_as_float(p.y);
                a1 = fmaf(w, x_in[(size_t)p.x * xstride + lane], a1);
                ws += w;
            }
            acc = fmaf(sc_in, acc + a1, sh_in * (1.0f + ws));
        }
        lds[(wid * 16 + nn) * LDS_PITCH + lane] = acc;
    }
    __syncthreads();

    // ---- Stage 1 GEMM: hidden = relu(xin @ W1^T + b1) ----
    float h[16];
#pragma unroll
    for (int jj = 0; jj < 16; ++jj) h[jj] = b1[wid * 16 + jj];
#pragma unroll 4
    for (int k = 0; k < DIM; ++k) {
        float xv = lds[lane * LDS_PITCH + k];
        const float* wr = W1T + k * DIM + wid * 16;   // uniform -> s_load
#pragma unroll
        for (int jj = 0; jj < 16; ++jj) h[jj] = fmaf(xv, wr[jj], h[jj]);
    }
#pragma unroll
    for (int jj = 0; jj < 16; ++jj) h[jj] = fmaxf(h[jj], 0.0f);
    __syncthreads();          // all lds (xin) reads done
#pragma unroll
    for (int jj = 0; jj < 16; ++jj) lds[lane * LDS_PITCH + wid * 16 + jj] = h[jj];
    __syncthreads();

    // ---- Stage 2 GEMM: o = relu(hidden @ W2^T + b2) ----
    float o[16];
#pragma unroll
    for (int jj = 0; jj < 16; ++jj) o[jj] = b2[wid * 16 + jj];
#pragma unroll 4
    for (int k = 0; k < DIM; ++k) {
        float hv = lds[lane * LDS_PITCH + k];
        const float* wr = W2T + k * DIM + wid * 16;
#pragma unroll
        for (int jj = 0; jj < 16; ++jj) o[jj] = fmaf(hv, wr[jj], o[jj]);
    }
    int n = nbase + lane;
    bool valid = (n < N_NODES);
#pragma unroll
    for (int jj = 0; jj < 16; ++jj) o[jj] = fmaxf(o[jj], 0.0f);
    if (valid) {
        float* orow = out + (size_t)n * OUTD + wid * 16;
#pragma unroll
        for (int jj = 0; jj < 16; jj += 4) {
            *(float4*)(orow + jj) = make_float4(o[jj], o[jj + 1], o[jj + 2], o[jj + 3]);
        }
    }

    // ---- BN stat partials: butterfly over 64 lanes; wave wid owns dims
    // [wid*16, wid*16+16). Non-atomic coalesced per-block store.
    float my_s = 0.0f, my_q = 0.0f;
#pragma unroll
    for (int jj = 0; jj < 16; ++jj) {
        float v = valid ? o[jj] : 0.0f;
        float vs = v, vq = v * v;
#pragma unroll
        for (int m = 1; m < 64; m <<= 1) {
            vs += __shfl_xor(vs, m);
            vq += __shfl_xor(vq, m);
        }
        if (lane == jj) { my_s = vs; my_q = vq; }
    }
    if (lane < 16) {
        size_t base = (size_t)blockIdx.x * 128 + wid * 16 + lane;
        pstat[base] = my_s;
        pstat[base + 64] = my_q;
    }
}

// ---------------------------------------------------------------------------
// Reduce per-block BN partials -> scale/shift for one layer (bn_prep folded).
__global__ void __launch_bounds__(1024) reduce_stats(
    const float* __restrict__ pstat,
    const float* __restrict__ gamma, const float* __restrict__ beta,
    float* __restrict__ ss /* [128]: scale|shift */) {
    __shared__ double part[8][128];
    __shared__ double tot[128];
    int t = threadIdx.x;
    int d = t & 127;
    int g = t >> 7;
    double s = 0.0;
    for (int b = g; b < NLBLK; b += 8)
        s += (double)pstat[(size_t)b * 128 + d];
    part[g][d] = s;
    __syncthreads();
    if (t < 128) {
        double x = 0.0;
#pragma unroll
        for (int k = 0; k < 8; ++k) x += part[k][d];
        tot[d] = x;
    }
    __syncthreads();
    if (t < 64) {
        double mu = tot[t] / (double)N_NODES;
        double var = tot[64 + t] / (double)N_NODES - mu * mu;
        float inv = (float)(1.0 / sqrt(var + (double)BN_EPS));
        float sc = gamma[t] * inv;
        ss[t] = sc;
        ss[64 + t] = beta[t] - (float)mu * sc;
    }
}

// ---------------------------------------------------------------------------
// Final pass: apply BN affine to xs IN PLACE (all 3 layers at once) and
// add-pool per graph. Grid (512 graphs, 4 parts), block 192.
__global__ void bn_pool(float* __restrict__ xs,
                        const int* __restrict__ batch,
                        const float* __restrict__ ss /* [3][128] */,
                        float* __restrict__ pooled) {
    int g = blockIdx.x;
    int part = blockIdx.y;   // 0..3
    int d = threadIdx.x;     // 0..191
    int l = d >> 6, dd = d & 63;
    float sc = ss[l * 128 + dd];
    float sh = ss[l * 128 + 64 + dd];
    int start, end;
    {
        int lo = 0, hi = N_NODES;
        while (lo < hi) { int m = (lo + hi) >> 1; if (batch[m] < g) lo = m + 1; else hi = m; }
        start = lo;
    }
    {
        int lo = start, hi = N_NODES;
        while (lo < hi) { int m = (lo + hi) >> 1; if (batch[m] <= g) lo = m + 1; else hi = m; }
        end = lo;
    }
    float acc = 0.0f;
    for (int n = start + part; n < end; n += 4) {
        float* p = xs + (size_t)n * OUTD + d;
        float v = fmaf(*p, sc, sh);
        *p = v;
        acc += v;
    }
    atomicAdd(&pooled[(size_t)g * OUTD + d], acc);
}

// ---------------------------------------------------------------------------
extern "C" void kernel_launch(void* const* d_in, const int* in_sizes, int n_in,
                              void* d_out, int out_size, void* d_ws, size_t ws_size,
                              hipStream_t stream) {
    const float* x0    = (const float*)d_in[0];
    const int*   ei    = (const int*)d_in[1];
    const float* ew    = (const float*)d_in[2];
    const int*   batch = (const int*)d_in[3];
    const float* W1    = (const float*)d_in[5];
    const float* b1    = (const float*)d_in[6];
    const float* W2    = (const float*)d_in[7];
    const float* b2    = (const float*)d_in[8];
    const float* gamma = (const float*)d_in[9];
    const float* beta  = (const float*)d_in[10];

    float* pooled = (float*)d_out;                      // [512, 192]
    float* xs     = pooled + (size_t)N_GRAPHS * OUTD;   // [100000, 192]

    const int* src = ei;
    const int* dst = ei + N_EDGES;

    const size_t aux_floats = (size_t)2 * N_LAYERS * DIM * DIM + 128
                            + (size_t)N_LAYERS * 128 + (size_t)NLBLK * 128;

    // ELL layout: pe[N*CAP] | cnt[N+4] | aux
    const size_t ell_bytes = (size_t)N_NODES * ELL_CAP * sizeof(int2)
                           + (size_t)(N_NODES + 4) * sizeof(int)
                           + aux_floats * sizeof(float);
    bool use_ell = (ws_size >= ell_bytes);

    int2*  pe;
    int*   seg;        // ELL: counts; CSR: offsets
    float* W1T;
    int*   csr_counts = nullptr;
    int*   csr_cursor = nullptr;
    int*   csr_bsum   = nullptr;

    if (use_ell) {
        pe   = (int2*)d_ws;                                   // 38.4 MB
        seg  = (int*)(pe + (size_t)N_NODES * ELL_CAP);        // cnt (N+4)
        W1T  = (float*)(seg + N_NODES + 4);
    } else {
        pe   = (int2*)d_ws;                                   // 9.6 MB
        csr_counts = (int*)(pe + N_EDGES);                    // (N+4)
        seg        = csr_counts + N_NODES + 4;                // offsets (N+4)
        csr_cursor = seg + N_NODES + 4;                       // (N+4)
        csr_bsum   = csr_cursor + N_NODES + 4;                // 128
        W1T  = (float*)(csr_bsum + 128);
    }
    float* W2T   = W1T + N_LAYERS * DIM * DIM;
    float* idaff = W2T + N_LAYERS * DIM * DIM;     // 128 floats
    float* ss    = idaff + 128;                    // 3*128 floats
    float* pstat = ss + N_LAYERS * 128;            // NLBLK*128 floats

    transpose_w<<<(N_LAYERS * DIM * DIM + 255) / 256, 256, 0, stream>>>(
        W1, W2, W1T, W2T, idaff);

    if (use_ell) {
        hipMemsetAsync(seg, 0, (size_t)(N_NODES + 4) * sizeof(int), stream);
        edge_bin_ell<<<(N_EDGES + 255) / 256, 256, 0, stream>>>(src, dst, ew, seg, pe);
    } else {
        hipMemsetAsync(csr_counts, 0, (size_t)(N_NODES + 4) * sizeof(int), stream);
        hist_kernel<<<(N_EDGES + 255) / 256, 256, 0, stream>>>(dst, csr_counts);
        scan_partial<<<NBLK, 256, 0, stream>>>(csr_counts, csr_bsum);
        scan_bsum<<<1, 128, 0, stream>>>(csr_bsum);
        scan_final<<<NBLK, 256, 0, stream>>>(csr_counts, csr_bsum, seg, csr_cursor);
        edge_bin_csr<<<(N_EDGES + 255) / 256, 256, 0, stream>>>(src, dst, ew,
                                                                csr_cursor, pe);
    }

    for (int i = 0; i < N_LAYERS; ++i) {
        const float* xin = (i == 0) ? x0 : (xs + (size_t)(i - 1) * DIM);
        int xstride = (i == 0) ? DIM : OUTD;
        const float* affine = (i == 0) ? idaff : (ss + (size_t)(i - 1) * 128);

        if (use_ell) {
            layer_kernel<true><<<NLBLK, 256, 0, stream>>>(
                xin, xstride, seg, pe, affine,
                W1T + (size_t)i * DIM * DIM, b1 + (size_t)i * DIM,
                W2T + (size_t)i * DIM * DIM, b2 + (size_t)i * DIM,
                xs + (size_t)i * DIM, pstat);
        } else {
            layer_kernel<false><<<NLBLK, 256, 0, stream>>>(
                xin, xstride, seg, pe, affine,
                W1T + (size_t)i * DIM * DIM, b1 + (size_t)i * DIM,
                W2T + (size_t)i * DIM * DIM, b2 + (size_t)i * DIM,
                xs + (size_t)i * DIM, pstat);
        }

        reduce_stats<<<1, 1024, 0, stream>>>(
            pstat, gamma + (size_t)i * DIM, beta + (size_t)i * DIM,
            ss + (size_t)i * 128);
    }

    hipMemsetAsync(pooled, 0, (size_t)N_GRAPHS * OUTD * sizeof(float), stream);
    dim3 pgrid(N_GRAPHS, 4);
    bn_pool<<<pgrid, OUTD, 0, stream>>>(xs, batch, ss, pooled);
}

// Round 9
// 542.580 us; speedup vs baseline: 2.3381x; 1.1953x over previous
//
#include <hip/hip_runtime.h>

#define N_NODES 100000
#define N_EDGES 1200000
#define DIM     64
#define N_LAYERS 3
#define N_GRAPHS 512
#define OUTD    192   // 3 * 64, concat layout
#define BN_EPS  1e-5f

#define ELL_CAP 48        // max in-degree capacity (Poisson(12) tail @48 ~1e-15)

#define SCAN_CHUNK 1024
#define NBLK ((N_NODES + SCAN_CHUNK - 1) / SCAN_CHUNK)    // 98

#define NPB 64            // nodes per block in layer_kernel
#define LDS_PITCH 65      // +1 pad -> 2-way bank aliasing only (free)
#define NLBLK ((N_NODES + NPB - 1) / NPB)                 // 1563

// ---------------------------------------------------------------------------
// Transpose W1/W2 (per layer): WT[l][k][j] = W[l][j][k]. Also writes the
// identity affine block (scale=1, shift=0) used by layer 0.
__global__ void transpose_w(const float* __restrict__ W1, const float* __restrict__ W2,
                            float* __restrict__ W1T, float* __restrict__ W2T,
                            float* __restrict__ idaff) {
    int idx = blockIdx.x * blockDim.x + threadIdx.x;  // L*64*64
    if (idx < 128) idaff[idx] = (idx < 64) ? 1.0f : 0.0f;
    if (idx >= N_LAYERS * DIM * DIM) return;
    int l = idx >> 12;
    int r = idx & 4095;
    int j = r >> 6;
    int k = r & 63;
    int dstp = (l << 12) + k * DIM + j;
    W1T[dstp] = W1[idx];
    W2T[dstp] = W2[idx];
}

// ---------------------------------------------------------------------------
// ELL binning, single pass (PROVEN R6/R8): 1.2M atomics spread over 100k node
// cursors (~12/address -> negligible contention; cf. R7's 196-cursor disaster).
// cursor[] ends up holding the per-node count.
__global__ void edge_bin_ell(const int* __restrict__ src, const int* __restrict__ dst,
                             const float* __restrict__ ew,
                             int* __restrict__ cursor, int2* __restrict__ pe) {
    int e = blockIdx.x * blockDim.x + threadIdx.x;
    if (e >= N_EDGES) return;
    int t = dst[e];
    int pos = atomicAdd(&cursor[t], 1);
    if (pos < ELL_CAP)
        pe[(size_t)t * ELL_CAP + pos] = make_int2(src[e], __float_as_int(ew[e]));
}

// ---------------------------------------------------------------------------
// CSR fallback path (only if ws too small for ELL).
__global__ void hist_kernel(const int* __restrict__ dst, int* __restrict__ counts) {
    int e = blockIdx.x * blockDim.x + threadIdx.x;
    if (e >= N_EDGES) return;
    atomicAdd(&counts[dst[e]], 1);
}

__global__ void scan_partial(const int* __restrict__ C, int* __restrict__ bsum) {
    __shared__ int lds[256];
    int b = blockIdx.x, t = threadIdx.x;
    int base = b * SCAN_CHUNK + t * 4;
    int s = 0;
#pragma unroll
    for (int k = 0; k < 4; ++k) {
        int i = base + k;
        if (i < N_NODES) s += C[i];
    }
    lds[t] = s;
    __syncthreads();
    for (int o = 128; o > 0; o >>= 1) {
        if (t < o) lds[t] += lds[t + o];
        __syncthreads();
    }
    if (t == 0) bsum[b] = lds[0];
}

__global__ void scan_bsum(int* __restrict__ bsum) {
    __shared__ int lds[128];
    int t = threadIdx.x;
    int v = (t < NBLK) ? bsum[t] : 0;
    lds[t] = v;
    __syncthreads();
    for (int o = 1; o < 128; o <<= 1) {
        int add = (t >= o) ? lds[t - o] : 0;
        __syncthreads();
        lds[t] += add;
        __syncthreads();
    }
    if (t < NBLK) bsum[t] = lds[t] - v;   // exclusive
}

__global__ void scan_final(const int* __restrict__ C, const int* __restrict__ bsum,
                           int* __restrict__ O, int* __restrict__ cursor) {
    __shared__ int lds[256];
    int b = blockIdx.x, t = threadIdx.x;
    int base = b * SCAN_CHUNK + t * 4;
    int v[4];
    int s = 0;
#pragma unroll
    for (int k = 0; k < 4; ++k) {
        int i = base + k;
        v[k] = (i < N_NODES) ? C[i] : 0;
        s += v[k];
    }
    lds[t] = s;
    __syncthreads();
    for (int o = 1; o < 256; o <<= 1) {
        int add = (t >= o) ? lds[t - o] : 0;
        __syncthreads();
        lds[t] += add;
        __syncthreads();
    }
    int off = bsum[b] + (lds[t] - s);
#pragma unroll
    for (int k = 0; k < 4; ++k) {
        int i = base + k;
        if (i < N_NODES) {
            O[i] = off;
            cursor[i] = off;
            off += v[k];
            if (i == N_NODES - 1) O[N_NODES] = off;
        }
    }
}

__global__ void edge_bin_csr(const int* __restrict__ src, const int* __restrict__ dst,
                             const float* __restrict__ ew,
                             int* __restrict__ cursor, int2* __restrict__ pe) {
    int e = blockIdx.x * blockDim.x + threadIdx.x;
    if (e >= N_EDGES) return;
    int t = dst[e];
    int pos = atomicAdd(&cursor[t], 1);
    pe[pos] = make_int2(src[e], __float_as_int(ew[e]));
}

// ---------------------------------------------------------------------------
// Fused layer (compile-time specialized on edge layout): gather(+x,
// +input-BN-affine, wsum inline) -> LDS -> MLP1 -> relu -> MLP2 -> relu
// -> global write + per-block BN stat partials.
// Block = 256 threads = 4 waves, 64 nodes; node id wave-uniform in gather so
// edge (src,w) pairs are s_loads (4 contiguous int2 = s_load_dwordx8);
// x_in[src] row is one coalesced 256B load. Edge loop unrolled x4 with 4
// independent accumulators -> 4 outstanding gather loads per wave (R8 showed
// ~48cyc/gather = latency-bound at ILP2; NO launch-bounds cap this time, cf R4).
// Input BN affine folded: agg_bn = sc*(x[n]+Σw·x[s]) + sh*(1+Σw).
template <bool ELL>
__global__ void __launch_bounds__(256) layer_kernel(
    const float* __restrict__ x_in, int xstride,
    const int* __restrict__ seg,     // ELL: counts; CSR: offsets (N+1)
    const int2* __restrict__ pe,
    const float* __restrict__ affine /* [128]: scale|shift of input */,
    const float* __restrict__ W1T, const float* __restrict__ b1,
    const float* __restrict__ W2T, const float* __restrict__ b2,
    float* __restrict__ out /* xs base + layer*64, row stride OUTD */,
    float* __restrict__ pstat /* [NLBLK][128]: sum|sumsq partials */) {
    __shared__ float lds[NPB * LDS_PITCH];
    int t = threadIdx.x;
    int lane = t & 63;
    int wid = __builtin_amdgcn_readfirstlane(t >> 6);   // wave id 0..3, SGPR
    int nbase = blockIdx.x * NPB;

    float sc_in = affine[lane];          // coalesced 256B, once
    float sh_in = affine[64 + lane];

    // ---- Phase 1: gather (16 nodes per wave, node id wave-uniform) ----
    for (int nn = 0; nn < 16; ++nn) {
        int n = nbase + wid * 16 + nn;
        float acc = 0.0f;
        if (n < N_NODES) {
            int beg, end;
            if (ELL) { beg = n * ELL_CAP; end = beg + seg[n]; }
            else     { beg = seg[n];      end = seg[n + 1]; }
            float a0 = x_in[(size_t)n * xstride + lane];   // coalesced 256B
            float a1 = 0.0f, a2 = 0.0f, a3 = 0.0f;
            float ws = 0.0f;                               // Σ edge weights
            int e = beg;
            for (; e + 4 <= end; e += 4) {
                int2 p0 = pe[e];
                int2 p1 = pe[e + 1];
                int2 p2 = pe[e + 2];
                int2 p3 = pe[e + 3];
                float w0 = __int_as_float(p0.y);
                float w1 = __int_as_float(p1.y);
                float w2 = __int_as_float(p2.y);
                float w3 = __int_as_float(p3.y);
                a0 = fmaf(w0, x_in[(size_t)p0.x * xstride + lane], a0);
                a1 = fmaf(w1, x_in[(size_t)p1.x * xstride + lane], a1);
                a2 = fmaf(w2, x_in[(size_t)p2.x * xstride + lane], a2);
                a3 = fmaf(w3, x_in[(size_t)p3.x * xstride + lane], a3);
                ws += (w0 + w1) + (w2 + w3);
            }
            for (; e < end; ++e) {
                int2 p = pe[e];
                float w = __int_as_float(p.y);
                a1 = fmaf(w, x_in[(size_t)p.x * xstride + lane], a1);
                ws += w;
            }
            acc = fmaf(sc_in, (a0 + a1) + (a2 + a3), sh_in * (1.0f + ws));
        }
        lds[(wid * 16 + nn) * LDS_PITCH + lane] = acc;
    }
    __syncthreads();

    // ---- Stage 1 GEMM: hidden = relu(xin @ W1^T + b1) ----
    float h[16];
#pragma unroll
    for (int jj = 0; jj < 16; ++jj) h[jj] = b1[wid * 16 + jj];
#pragma unroll 4
    for (int k = 0; k < DIM; ++k) {
        float xv = lds[lane * LDS_PITCH + k];
        const float* wr = W1T + k * DIM + wid * 16;   // uniform -> s_load
#pragma unroll
        for (int jj = 0; jj < 16; ++jj) h[jj] = fmaf(xv, wr[jj], h[jj]);
    }
#pragma unroll
    for (int jj = 0; jj < 16; ++jj) h[jj] = fmaxf(h[jj], 0.0f);
    __syncthreads();          // all lds (xin) reads done
#pragma unroll
    for (int jj = 0; jj < 16; ++jj) lds[lane * LDS_PITCH + wid * 16 + jj] = h[jj];
    __syncthreads();

    // ---- Stage 2 GEMM: o = relu(hidden @ W2^T + b2) ----
    float o[16];
#pragma unroll
    for (int jj = 0; jj < 16; ++jj) o[jj] = b2[wid * 16 + jj];
#pragma unroll 4
    for (int k = 0; k < DIM; ++k) {
        float hv = lds[lane * LDS_PITCH + k];
        const float* wr = W2T + k * DIM + wid * 16;
#pragma unroll
        for (int jj = 0; jj < 16; ++jj) o[jj] = fmaf(hv, wr[jj], o[jj]);
    }
    int n = nbase + lane;
    bool valid = (n < N_NODES);
#pragma unroll
    for (int jj = 0; jj < 16; ++jj) o[jj] = fmaxf(o[jj], 0.0f);
    if (valid) {
        float* orow = out + (size_t)n * OUTD + wid * 16;
#pragma unroll
        for (int jj = 0; jj < 16; jj += 4) {
            *(float4*)(orow + jj) = make_float4(o[jj], o[jj + 1], o[jj + 2], o[jj + 3]);
        }
    }

    // ---- BN stat partials: butterfly over 64 lanes; wave wid owns dims
    // [wid*16, wid*16+16). Non-atomic coalesced per-block store.
    float my_s = 0.0f, my_q = 0.0f;
#pragma unroll
    for (int jj = 0; jj < 16; ++jj) {
        float v = valid ? o[jj] : 0.0f;
        float vs = v, vq = v * v;
#pragma unroll
        for (int m = 1; m < 64; m <<= 1) {
            vs += __shfl_xor(vs, m);
            vq += __shfl_xor(vq, m);
        }
        if (lane == jj) { my_s = vs; my_q = vq; }
    }
    if (lane < 16) {
        size_t base = (size_t)blockIdx.x * 128 + wid * 16 + lane;
        pstat[base] = my_s;
        pstat[base + 64] = my_q;
    }
}

// ---------------------------------------------------------------------------
// Reduce per-block BN partials -> scale/shift (bn_prep folded).
// PARALLELIZED (R8's was 1 block, latency-bound): 8 blocks, block b owns dims
// [b*8, b*8+8); 16 groups of 16 threads stride over the 1563 pstat rows.
__global__ void __launch_bounds__(256) reduce_stats(
    const float* __restrict__ pstat,
    const float* __restrict__ gamma, const float* __restrict__ beta,
    float* __restrict__ ss /* [128]: scale|shift */) {
    __shared__ double part[16][16];
    int b = blockIdx.x;            // 0..7
    int t = threadIdx.x;
    int slot = t & 15;             // 0..7 -> sum(d), 8..15 -> sumsq(d)
    int g = t >> 4;                // group 0..15
    int d = b * 8 + (slot & 7);
    int off = (slot < 8) ? 0 : 64;
    double s = 0.0;
    for (int blk = g; blk < NLBLK; blk += 16)
        s += (double)pstat[(size_t)blk * 128 + off + d];
    part[g][slot] = s;
    __syncthreads();
    if (t < 16) {
        double x = 0.0;
#pragma unroll
        for (int k = 0; k < 16; ++k) x += part[k][t];
        part[0][t] = x;            // column t only -> no hazard
    }
    __syncthreads();
    if (t < 8) {
        int dd = b * 8 + t;
        double mu = part[0][t] / (double)N_NODES;
        double var = part[0][8 + t] / (double)N_NODES - mu * mu;
        float inv = (float)(1.0 / sqrt(var + (double)BN_EPS));
        float sc = gamma[dd] * inv;
        ss[dd] = sc;
        ss[64 + dd] = beta[dd] - (float)mu * sc;
    }
}

// ---------------------------------------------------------------------------
// Final pass: apply BN affine to xs IN PLACE (all 3 layers at once) and
// add-pool per graph. Grid (512 graphs, 4 parts), block 192.
__global__ void bn_pool(float* __restrict__ xs,
                        const int* __restrict__ batch,
                        const float* __restrict__ ss /* [3][128] */,
                        float* __restrict__ pooled) {
    int g = blockIdx.x;
    int part = blockIdx.y;   // 0..3
    int d = threadIdx.x;     // 0..191
    int l = d >> 6, dd = d & 63;
    float sc = ss[l * 128 + dd];
    float sh = ss[l * 128 + 64 + dd];
    int start, end;
    {
        int lo = 0, hi = N_NODES;
        while (lo < hi) { int m = (lo + hi) >> 1; if (batch[m] < g) lo = m + 1; else hi = m; }
        start = lo;
    }
    {
        int lo = start, hi = N_NODES;
        while (lo < hi) { int m = (lo + hi) >> 1; if (batch[m] <= g) lo = m + 1; else hi = m; }
        end = lo;
    }
    float acc = 0.0f;
    for (int n = start + part; n < end; n += 4) {
        float* p = xs + (size_t)n * OUTD + d;
        float v = fmaf(*p, sc, sh);
        *p = v;
        acc += v;
    }
    atomicAdd(&pooled[(size_t)g * OUTD + d], acc);
}

// ---------------------------------------------------------------------------
extern "C" void kernel_launch(void* const* d_in, const int* in_sizes, int n_in,
                              void* d_out, int out_size, void* d_ws, size_t ws_size,
                              hipStream_t stream) {
    const float* x0    = (const float*)d_in[0];
    const int*   ei    = (const int*)d_in[1];
    const float* ew    = (const float*)d_in[2];
    const int*   batch = (const int*)d_in[3];
    const float* W1    = (const float*)d_in[5];
    const float* b1    = (const float*)d_in[6];
    const float* W2    = (const float*)d_in[7];
    const float* b2    = (const float*)d_in[8];
    const float* gamma = (const float*)d_in[9];
    const float* beta  = (const float*)d_in[10];

    float* pooled = (float*)d_out;                      // [512, 192]
    float* xs     = pooled + (size_t)N_GRAPHS * OUTD;   // [100000, 192]

    const int* src = ei;
    const int* dst = ei + N_EDGES;

    const size_t aux_floats = (size_t)2 * N_LAYERS * DIM * DIM + 128
                            + (size_t)N_LAYERS * 128 + (size_t)NLBLK * 128;

    // ELL layout: pe[N*CAP] | cnt[N+4] | aux
    const size_t ell_bytes = (size_t)N_NODES * ELL_CAP * sizeof(int2)
                           + (size_t)(N_NODES + 4) * sizeof(int)
                           + aux_floats * sizeof(float);
    bool use_ell = (ws_size >= ell_bytes);

    int2*  pe;
    int*   seg;        // ELL: counts; CSR: offsets
    float* W1T;
    int*   csr_counts = nullptr;
    int*   csr_cursor = nullptr;
    int*   csr_bsum   = nullptr;

    if (use_ell) {
        pe   = (int2*)d_ws;                                   // 38.4 MB
        seg  = (int*)(pe + (size_t)N_NODES * ELL_CAP);        // cnt (N+4)
        W1T  = (float*)(seg + N_NODES + 4);
    } else {
        pe   = (int2*)d_ws;                                   // 9.6 MB
        csr_counts = (int*)(pe + N_EDGES);                    // (N+4)
        seg        = csr_counts + N_NODES + 4;                // offsets (N+4)
        csr_cursor = seg + N_NODES + 4;                       // (N+4)
        csr_bsum   = csr_cursor + N_NODES + 4;                // 128
        W1T  = (float*)(csr_bsum + 128);
    }
    float* W2T   = W1T + N_LAYERS * DIM * DIM;
    float* idaff = W2T + N_LAYERS * DIM * DIM;     // 128 floats
    float* ss    = idaff + 128;                    // 3*128 floats
    float* pstat = ss + N_LAYERS * 128;            // NLBLK*128 floats

    transpose_w<<<(N_LAYERS * DIM * DIM + 255) / 256, 256, 0, stream>>>(
        W1, W2, W1T, W2T, idaff);

    if (use_ell) {
        hipMemsetAsync(seg, 0, (size_t)(N_NODES + 4) * sizeof(int), stream);
        edge_bin_ell<<<(N_EDGES + 255) / 256, 256, 0, stream>>>(src, dst, ew, seg, pe);
    } else {
        hipMemsetAsync(csr_counts, 0, (size_t)(N_NODES + 4) * sizeof(int), stream);
        hist_kernel<<<(N_EDGES + 255) / 256, 256, 0, stream>>>(dst, csr_counts);
        scan_partial<<<NBLK, 256, 0, stream>>>(csr_counts, csr_bsum);
        scan_bsum<<<1, 128, 0, stream>>>(csr_bsum);
        scan_final<<<NBLK, 256, 0, stream>>>(csr_counts, csr_bsum, seg, csr_cursor);
        edge_bin_csr<<<(N_EDGES + 255) / 256, 256, 0, stream>>>(src, dst, ew,
                                                                csr_cursor, pe);
    }

    for (int i = 0; i < N_LAYERS; ++i) {
        const float* xin = (i == 0) ? x0 : (xs + (size_t)(i - 1) * DIM);
        int xstride = (i == 0) ? DIM : OUTD;
        const float* affine = (i == 0) ? idaff : (ss + (size_t)(i - 1) * 128);

        if (use_ell) {
            layer_kernel<true><<<NLBLK, 256, 0, stream>>>(
                xin, xstride, seg, pe, affine,
                W1T + (size_t)i * DIM * DIM, b1 + (size_t)i * DIM,
                W2T + (size_t)i * DIM * DIM, b2 + (size_t)i * DIM,
                xs + (size_t)i * DIM, pstat);
        } else {
            layer_kernel<false><<<NLBLK, 256, 0, stream>>>(
                xin, xstride, seg, pe, affine,
                W1T + (size_t)i * DIM * DIM, b1 + (size_t)i * DIM,
                W2T + (size_t)i * DIM * DIM, b2 + (size_t)i * DIM,
                xs + (size_t)i * DIM, pstat);
        }

        reduce_stats<<<8, 256, 0, stream>>>(
            pstat, gamma + (size_t)i * DIM, beta + (size_t)i * DIM,
            ss + (size_t)i * 128);
    }

    hipMemsetAsync(pooled, 0, (size_t)N_GRAPHS * OUTD * sizeof(float), stream);
    dim3 pgrid(N_GRAPHS, 4);
    bn_pool<<<pgrid, OUTD, 0, stream>>>(xs, batch, ss, pooled);
}